// Round 7
// baseline (259.470 us; speedup 1.0000x reference)
//
#include <hip/hip_runtime.h>
#include <hip/hip_bf16.h>
#include <stdint.h>

#define Bb 4
#define SEQ 2048
#define Ee 1024
#define Hh 16
#define Dh 64
#define Mm (Bb*SEQ)   // 8192

typedef __attribute__((ext_vector_type(8))) short bfrag;    // 8 bf16 (4 VGPRs)
typedef __attribute__((ext_vector_type(4))) float f32x4;
typedef __attribute__((ext_vector_type(16))) float f32x16;
typedef __attribute__((ext_vector_type(4))) unsigned u32x4;
typedef unsigned short u16;

__device__ __forceinline__ u16 f2bf(float x) {
  __hip_bfloat16 h = __float2bfloat16(x);
  return *reinterpret_cast<u16*>(&h);
}

__device__ __forceinline__ void gll16(const void* g, void* l) {
  __builtin_amdgcn_global_load_lds(
      (const __attribute__((address_space(1))) void*)g,
      (__attribute__((address_space(3))) void*)l, 16, 0, 0);
}

// ---------------- fused cast fp32 -> bf16 ----------------
__global__ __launch_bounds__(256) void cast_all(
    const float* __restrict__ x,  const float* __restrict__ wq,
    const float* __restrict__ wk, const float* __restrict__ wv,
    const float* __restrict__ wo,
    u16* __restrict__ xb, u16* __restrict__ wqb, u16* __restrict__ wkb,
    u16* __restrict__ wvb, u16* __restrict__ wob)
{
  int idx = blockIdx.x * 256 + threadIdx.x;
  const float* src; u16* dst; int off;
  if (idx < 2097152) { src = x; dst = xb; off = idx; }
  else {
    int t = idx - 2097152;
    int seg = t >> 18;
    off = t & 262143;
    src = (seg == 0) ? wq : (seg == 1) ? wk : (seg == 2) ? wv : wo;
    dst = (seg == 0) ? wqb : (seg == 1) ? wkb : (seg == 2) ? wvb : wob;
  }
  float4 v = reinterpret_cast<const float4*>(src)[off];
  ushort4 o;
  o.x = f2bf(v.x); o.y = f2bf(v.y); o.z = f2bf(v.z); o.w = f2bf(v.w);
  reinterpret_cast<ushort4*>(dst)[off] = o;
}

// ---------------- GEMM: C[m,f] = sum_e A[m,e]*W[f,e] + bias[f] ----------------
// 128x128 tile, BK=64, 4 waves. Double-buffered LDS (prefetch t+1 before compute t),
// XOR-8 swizzle on staging (pre-swizzled global source) + reads, setprio on MFMA.
// OUTMODE 0: z==0 Q (scaled 1/8) / z==1 K -> scatter [B,H,S,D];
//            z==2 V -> fused transpose+permute to [B,H,D,S'] (s' = s bits2,3 swapped)
// OUTMODE 1: fp32 out [M,N]
template<int OUTMODE>
__global__ __launch_bounds__(256) void gemm_bt(
    const u16* __restrict__ A,
    const u16* __restrict__ W0, const u16* __restrict__ W1, const u16* __restrict__ W2,
    const float* __restrict__ b0, const float* __restrict__ b1, const float* __restrict__ b2,
    void* __restrict__ outp, u16* __restrict__ vt, int K, int N)
{
  __shared__ __align__(16) u16 smem[32768];   // 64 KB: 2 slots x (As 8192 | Bs 8192)
  const int tid  = threadIdx.x;
  const int lane = tid & 63;
  const int wid  = tid >> 6;
  const int bm = blockIdx.x * 128;
  const int bn = blockIdx.y * 128;
  const int z  = blockIdx.z;
  const u16*  Wp = (z == 0) ? W0 : (z == 1) ? W1 : W2;
  const float* bp = (z == 0) ? b0 : (z == 1) ? b1 : b2;
  const int wr = (wid >> 1) * 64, wc = (wid & 1) * 64;
  const int lr = lane & 15, lk = (lane >> 4) * 8;
  const int kx = (lr & 7) << 3;               // read-side XOR key (row&7 == lr&7)

  // staging source offsets: swizzled global col, linear LDS dest (rule 21)
  size_t aoff[4], boff[4];
#pragma unroll
  for (int p = 0; p < 4; ++p) {
    int flat = p * 2048 + tid * 8;
    int r = flat >> 6, c = flat & 63;
    int cs = c ^ ((r & 7) << 3);
    aoff[p] = (size_t)(bm + r) * K + cs;
    boff[p] = (size_t)(bn + r) * K + cs;
  }

  f32x4 acc[4][4] = {};

  auto stage = [&](int kt, int s) {
    u16* As = smem + s * 16384;
    u16* Bs = As + 8192;
#pragma unroll
    for (int p = 0; p < 4; ++p)
      gll16(A + aoff[p] + kt, As + p * 2048 + tid * 8);
#pragma unroll
    for (int p = 0; p < 4; ++p)
      gll16(Wp + boff[p] + kt, Bs + p * 2048 + tid * 8);
  };

  const int NT = K >> 6;
  stage(0, 0);
  __syncthreads();
  for (int t = 0; t < NT; ++t) {
    const int cur = t & 1;
    if (t + 1 < NT) stage((t + 1) << 6, cur ^ 1);   // prefetch overlaps compute
    const u16* As = smem + cur * 16384;
    const u16* Bs = As + 8192;
#pragma unroll
    for (int kk = 0; kk < 2; ++kk) {
      bfrag a[4], b[4];
      const int col = (kk * 32 + lk) ^ kx;
#pragma unroll
      for (int i = 0; i < 4; ++i)
        a[i] = *reinterpret_cast<const bfrag*>(&As[(wr + i * 16 + lr) * 64 + col]);
#pragma unroll
      for (int j = 0; j < 4; ++j)
        b[j] = *reinterpret_cast<const bfrag*>(&Bs[(wc + j * 16 + lr) * 64 + col]);
      __builtin_amdgcn_s_setprio(1);
#pragma unroll
      for (int i = 0; i < 4; ++i)
#pragma unroll
        for (int j = 0; j < 4; ++j)
          acc[i][j] = __builtin_amdgcn_mfma_f32_16x16x32_bf16(a[i], b[j], acc[i][j], 0, 0, 0);
      __builtin_amdgcn_s_setprio(0);
    }
    __syncthreads();   // drains prefetch vmcnt + releases the other slot
  }

  float bias[4];
#pragma unroll
  for (int j = 0; j < 4; ++j) bias[j] = bp[bn + wc + j * 16 + (lane & 15)];

  if (OUTMODE == 0) {
    const float scl = (z == 0) ? 0.125f : 1.0f;   // fold softsign's /8 into Q
    u16* cst = smem;   // [128][128] bf16, XOR-8 swizzled cols
#pragma unroll
    for (int i = 0; i < 4; ++i)
#pragma unroll
      for (int j = 0; j < 4; ++j)
#pragma unroll
        for (int e = 0; e < 4; ++e) {
          int row = wr + i * 16 + (lane >> 4) * 4 + e;
          int c2  = wc + j * 16 + (lane & 15);
          cst[row * 128 + (c2 ^ ((row & 7) << 3))] = f2bf((acc[i][j][e] + bias[j]) * scl);
        }
    __syncthreads();
    if (z < 2) {
      u16* outb = (u16*)outp + (size_t)z * (size_t)Mm * Ee;
#pragma unroll
      for (int p = 0; p < 8; ++p) {
        int chunk = p * 256 + tid;        // 2048 chunks of 8 bf16
        int r = chunk >> 4;
        int c = (chunk & 15) * 8;
        int m = bm + r, f = bn + c;
        u16* dst = outb + ((((size_t)(m >> 11) * Hh + (f >> 6)) * SEQ + (m & 2047)) * Dh + (f & 63));
        *reinterpret_cast<bfrag*>(dst) =
            *reinterpret_cast<const bfrag*>(&cst[r * 128 + (c ^ ((r & 7) << 3))]);
      }
    } else {
      // V: write transposed+permuted [B,H,D,S'] directly (replaces transpose_v kernel)
      const int bq = bm >> 11;
      const int s_base = bm & 2047;
#pragma unroll
      for (int p = 0; p < 8; ++p) {
        int chunk = p * 256 + tid;        // 2048: d = chunk>>4 (0..127), sc = chunk&15
        int d = chunk >> 4, sc = chunk & 15;
        int f = bn + d;
        int h = f >> 6, dl = f & 63;
        bfrag o;
#pragma unroll
        for (int e = 0; e < 8; ++e) {
          int sp = sc * 8 + e;                                       // s' local
          int ss = (sp & ~12) | ((sp & 4) << 1) | ((sp & 8) >> 1);   // swap bits 2,3
          o[e] = (short)cst[ss * 128 + (d ^ ((ss & 7) << 3))];
        }
        *reinterpret_cast<bfrag*>(
            &vt[((size_t)((bq * Hh + h) * Dh + dl)) * SEQ + s_base + sc * 8]) = o;
      }
    }
  } else {
    float* outf = (float*)outp;
    float* cf = reinterpret_cast<float*>(smem);   // [64][128] fp32 = 32 KB
#pragma unroll
    for (int half = 0; half < 2; ++half) {
      __syncthreads();
      if ((wid >> 1) == half) {
#pragma unroll
        for (int i = 0; i < 4; ++i)
#pragma unroll
          for (int j = 0; j < 4; ++j)
#pragma unroll
            for (int e = 0; e < 4; ++e)
              cf[(i * 16 + (lane >> 4) * 4 + e) * 128 + wc + j * 16 + (lane & 15)] =
                  acc[i][j][e] + bias[j];
      }
      __syncthreads();
#pragma unroll
      for (int p = 0; p < 8; ++p) {
        int chunk = p * 256 + tid;
        int r = chunk >> 5;
        int c = (chunk & 31) * 4;
        *reinterpret_cast<float4*>(&outf[(size_t)(bm + half * 64 + r) * N + bn + c]) =
            *reinterpret_cast<const float4*>(&cf[r * 128 + c]);
      }
    }
  }
}

// ---------------- fused attention (softsign), swapped-QK^T 32x32 ---------------
// 512 blocks (2/CU), 4 waves x 64 q-rows (halves LDS-read bytes per FLOP vs 32q).
// K/V 64-tiles double-buffered in LDS packed as [32 lds-rows][128 cols] with 4-bit
// XOR swizzle. Q pre-scaled by 1/8 -> P = s/(1+|s|), truncation-packed via v_perm.
__global__ __launch_bounds__(256) void attn_kernel(
    const u16* __restrict__ qg_, const u16* __restrict__ kg,
    const u16* __restrict__ vtg, u16* __restrict__ ctx)
{
  __shared__ __align__(16) u16 smem[16384];   // K dbuf 2x4096 | V dbuf 2x4096 (32 KB)
  const int tid  = threadIdx.x;
  const int lane = tid & 63;
  const int wid  = tid >> 6;
  const int ql = lane & 31;
  const int hi = lane >> 5;

  // XCD-bijective swizzle: 512 wgs, 64/XCD -> 8 consecutive bh per XCD (K/V L2-fit)
  const int orig = blockIdx.x;
  const int swz  = (orig & 7) * 64 + (orig >> 3);
  const int bh = swz >> 3;
  const int q0 = (swz & 7) * 256;

  const u16* qb  = qg_ + (size_t)bh * SEQ * Dh;
  const u16* kb  = kg  + (size_t)bh * SEQ * Dh;
  const u16* vtb = vtg + (size_t)bh * Dh * SEQ;

  // Q frags (B operand), 2 groups of 32 q: lane -> Q[q][db*16+hi*8..+7] (pre-scaled /8)
  bfrag qf[2][4];
#pragma unroll
  for (int qg2 = 0; qg2 < 2; ++qg2)
#pragma unroll
    for (int db = 0; db < 4; ++db)
      qf[qg2][db] = *reinterpret_cast<const bfrag*>(
          &qb[(size_t)(q0 + wid * 64 + qg2 * 32 + ql) * Dh + db * 16 + hi * 8]);

  // staging source offsets (32-bit, precomputed; dest stays lane-linear)
  int koff[2], voff[2];
#pragma unroll
  for (int p = 0; p < 2; ++p) {
    int f = p * 2048 + tid * 8;
    int lrow = f >> 7;
    int log7 = (f & 127) ^ ((lrow & 15) << 3);
    int r = lrow * 2 + (log7 >> 6);
    int c = log7 & 63;
    koff[p] = r * 64 + c;        // K tile: row r (k), col c (d); + kt*64 per tile
    voff[p] = r * SEQ + c;       // Vt tile: row r (d), col c (s'); + kt per tile
  }

  f32x16 o[2][2] = {};   // o[qg][dh]: rows=q (C-layout), cols=d

  auto stage = [&](int kt, int buf) {
#pragma unroll
    for (int p = 0; p < 2; ++p)
      gll16(kb + (size_t)kt * 64 + koff[p], smem + buf * 4096 + p * 2048 + tid * 8);
#pragma unroll
    for (int p = 0; p < 2; ++p)
      gll16(vtb + kt + voff[p], smem + 8192 + buf * 4096 + p * 2048 + tid * 8);
  };

  stage(0, 0);
  __syncthreads();

  for (int ti = 0; ti < 32; ++ti) {
    const int cur = ti & 1;
    if (ti < 31) stage((ti + 1) * 64, cur ^ 1);   // prefetch overlaps compute
    const u16* Kb = smem + cur * 4096;
    const u16* Vb = smem + 8192 + cur * 4096;

#pragma unroll
    for (int kh = 0; kh < 2; ++kh) {
      // S^T = mfma(A=K, B=Q): lane owns q=ql column; accumulate over 4 d-blocks.
      // K frags read ONCE per kh, reused for both q-groups.
      f32x16 s0 = {}, s1 = {};
      __builtin_amdgcn_s_setprio(1);
#pragma unroll
      for (int db = 0; db < 4; ++db) {
        const int krow = kh * 32 + ql;
        const int lr2 = krow >> 1;
        const int log7 = ((krow & 1) << 6) | (db * 16 + hi * 8);
        bfrag ka = *reinterpret_cast<const bfrag*>(
            &Kb[lr2 * 128 + (log7 ^ ((lr2 & 15) << 3))]);
        s0 = __builtin_amdgcn_mfma_f32_32x32x16_bf16(ka, qf[0][db], s0, 0, 0, 0);
        s1 = __builtin_amdgcn_mfma_f32_32x32x16_bf16(ka, qf[1][db], s1, 0, 0, 0);
      }
      __builtin_amdgcn_s_setprio(0);

      // softsign: P = s/(1+|s|); truncation-pack 2 f32 -> 1 u32 via v_perm
      unsigned pw0[8], pw1[8];
#pragma unroll
      for (int r = 0; r < 8; ++r) {
        float a = s0[2 * r], b = s0[2 * r + 1];
        float pa_ = a * __builtin_amdgcn_rcpf(1.0f + __builtin_fabsf(a));
        float pb_ = b * __builtin_amdgcn_rcpf(1.0f + __builtin_fabsf(b));
        pw0[r] = __builtin_amdgcn_perm(__builtin_bit_cast(unsigned, pb_),
                                       __builtin_bit_cast(unsigned, pa_),
                                       0x07060302u);
      }
#pragma unroll
      for (int r = 0; r < 8; ++r) {
        float a = s1[2 * r], b = s1[2 * r + 1];
        float pa_ = a * __builtin_amdgcn_rcpf(1.0f + __builtin_fabsf(a));
        float pb_ = b * __builtin_amdgcn_rcpf(1.0f + __builtin_fabsf(b));
        pw1[r] = __builtin_amdgcn_perm(__builtin_bit_cast(unsigned, pb_),
                                       __builtin_bit_cast(unsigned, pa_),
                                       0x07060302u);
      }
      u32x4 w00 = {pw0[0], pw0[1], pw0[2], pw0[3]};
      u32x4 w01 = {pw0[4], pw0[5], pw0[6], pw0[7]};
      u32x4 w10 = {pw1[0], pw1[1], pw1[2], pw1[3]};
      u32x4 w11 = {pw1[4], pw1[5], pw1[6], pw1[7]};
      bfrag pa00 = __builtin_bit_cast(bfrag, w00);   // [qg][tt]
      bfrag pa01 = __builtin_bit_cast(bfrag, w01);
      bfrag pa10 = __builtin_bit_cast(bfrag, w10);
      bfrag pa11 = __builtin_bit_cast(bfrag, w11);

      // O += P @ V  (V k-rows pre-permuted to match S^T register order);
      // V frags read once per (tt,dh), reused for both q-groups.
      __builtin_amdgcn_s_setprio(1);
#pragma unroll
      for (int tt = 0; tt < 2; ++tt)
#pragma unroll
        for (int dh = 0; dh < 2; ++dh) {
          const int vrow = dh * 32 + ql;
          const int lr2 = vrow >> 1;
          const int log7 = ((vrow & 1) << 6) | (kh * 32 + tt * 16 + hi * 8);
          bfrag vb = *reinterpret_cast<const bfrag*>(
              &Vb[lr2 * 128 + (log7 ^ ((lr2 & 15) << 3))]);
          o[0][dh] = __builtin_amdgcn_mfma_f32_32x32x16_bf16(tt ? pa01 : pa00, vb, o[0][dh], 0, 0, 0);
          o[1][dh] = __builtin_amdgcn_mfma_f32_32x32x16_bf16(tt ? pa11 : pa10, vb, o[1][dh], 0, 0, 0);
        }
      __builtin_amdgcn_s_setprio(0);
    }
    __syncthreads();   // drains prefetch vmcnt + releases buffers
  }

  // epilogue: O rows q=(r&3)+8*(r>>2)+4*hi, col d=dh*32+ql; via LDS to coalesce
  u16* cst = smem;   // [256][64] = 32 KB
#pragma unroll
  for (int qg2 = 0; qg2 < 2; ++qg2)
#pragma unroll
    for (int dh = 0; dh < 2; ++dh)
#pragma unroll
      for (int r = 0; r < 16; ++r) {
        int qrow = wid * 64 + qg2 * 32 + (r & 3) + 8 * (r >> 2) + 4 * hi;
        cst[qrow * 64 + dh * 32 + ql] = f2bf(o[qg2][dh][r]);
      }
  __syncthreads();
  const int b = bh >> 4, h = bh & 15;
#pragma unroll
  for (int p = 0; p < 8; ++p) {
    int chunk = p * 256 + tid;          // 2048 chunks of 8 bf16
    int r = chunk >> 3, cc = (chunk & 7) * 8;
    u16* dst = ctx + ((size_t)(b * SEQ + q0 + r) * Ee + h * Dh + cc);
    *reinterpret_cast<bfrag*>(dst) = *reinterpret_cast<const bfrag*>(&cst[r * 64 + cc]);
  }
}

// ---------------- launch ----------------
extern "C" void kernel_launch(void* const* d_in, const int* in_sizes, int n_in,
                              void* d_out, int out_size, void* d_ws, size_t ws_size,
                              hipStream_t stream)
{
  const float* x  = (const float*)d_in[0];
  const float* Wq = (const float*)d_in[1];
  const float* bq = (const float*)d_in[2];
  const float* Wk = (const float*)d_in[3];
  const float* bk = (const float*)d_in[4];
  const float* Wv = (const float*)d_in[5];
  const float* bv = (const float*)d_in[6];
  const float* Wo = (const float*)d_in[7];
  const float* bo = (const float*)d_in[8];
  float* out = (float*)d_out;

  u16* ws  = (u16*)d_ws;
  u16* xb  = ws;                         // A input; dead after QKV GEMM -> reused as ctx
  u16* wqb = ws + 8388608;
  u16* wkb = wqb + 1048576;
  u16* wvb = wkb + 1048576;
  u16* wob = wvb + 1048576;
  u16* qkv = wob + 1048576;              // Q,K in [B,H,S,D]; slot 2 = Vt [B,H,D,S']
  u16* q_  = qkv;
  u16* k_  = qkv + 8388608;
  u16* vt  = qkv + 2 * 8388608;          // V written transposed by gemm z==2
  u16* ctx = xb;                         // reuse xb after QKV gemm

  cast_all<<<12288, 256, 0, stream>>>(x, Wq, Wk, Wv, Wo, xb, wqb, wkb, wvb, wob);

  // QKV projections; z==2 fuses the V transpose (writes vt)
  gemm_bt<0><<<dim3(64, 8, 3), 256, 0, stream>>>(xb, wqb, wkb, wvb, bq, bk, bv,
                                                 qkv, vt, Ee, Ee);
  // fused softsign attention -> ctx [B,S,E] bf16
  attn_kernel<<<512, 256, 0, stream>>>(q_, k_, vt, ctx);
  // output projection, fp32 out
  gemm_bt<1><<<dim3(64, 8, 1), 256, 0, stream>>>(ctx, wob, wob, wob, bo, bo, bo,
                                                 out, nullptr, Ee, Ee);
}